// Round 1
// baseline (399.136 us; speedup 1.0000x reference)
//
#include <hip/hip_runtime.h>
#include <hip/hip_bf16.h>

using bf16 = __hip_bfloat16;
typedef __attribute__((ext_vector_type(8))) short short8;   // 8 bf16 = 4 VGPRs (MFMA A/B frag)
typedef __attribute__((ext_vector_type(4))) float floatx4;  // MFMA C/D frag

#define LDS_PAD 8  // bf16 elements -> keeps 16B alignment (stride 80B), 2-way-conflict-free

// ---------------------------------------------------------------------------
// C[M x N] = scale * A[M x K] (row-major bf16) * Bt[N x K]^T (row-major bf16)
// 128x128 block tile, BK=32, 256 threads = 4 waves in 2x2, each wave 64x64
// via 4x4 grid of v_mfma_f32_16x16x32_bf16.
// Verified layouts (cdna_hip_programming.md §3):
//   A frag: lane holds A[m = lane&15][k = (lane>>4)*8 + j], j=0..7
//   C/D   : col = lane&15, row = (lane>>4)*4 + reg
// ---------------------------------------------------------------------------
template <typename OutT>
__global__ __launch_bounds__(256) void gemm_bt(
    const bf16* __restrict__ A, const bf16* __restrict__ B, OutT* __restrict__ C,
    int M, int N, int K, long strideA, long strideB, long strideC, float scale)
{
    const int b = blockIdx.z;
    A += (long)b * strideA;
    B += (long)b * strideB;
    C += (long)b * strideC;

    const int bm = blockIdx.y * 128;
    const int bn = blockIdx.x * 128;
    const int tid = threadIdx.x;
    const int lane = tid & 63;
    const int wave = tid >> 6;
    const int wm = (wave >> 1) * 64;
    const int wn = (wave & 1) * 64;

    __shared__ bf16 As[128][32 + LDS_PAD];
    __shared__ bf16 Bs[128][32 + LDS_PAD];

    floatx4 acc[4][4];
#pragma unroll
    for (int i = 0; i < 4; i++)
#pragma unroll
        for (int j = 0; j < 4; j++) acc[i][j] = (floatx4)(0.0f);

    // staging: each thread moves 8 bf16 (16B) x2 rows for A and B per K-tile
    const int r0 = tid >> 2;          // 0..63
    const int c0 = (tid & 3) * 8;     // 0,8,16,24

    const int mrow = lane & 15;
    const int krow = (lane >> 4) * 8;

    for (int kb = 0; kb < K; kb += 32) {
        const bf16* Ag = A + (long)(bm + r0) * K + kb + c0;
        const bf16* Bg = B + (long)(bn + r0) * K + kb + c0;
        *(short8*)(&As[r0][c0])      = *(const short8*)(Ag);
        *(short8*)(&As[r0 + 64][c0]) = *(const short8*)(Ag + 64L * K);
        *(short8*)(&Bs[r0][c0])      = *(const short8*)(Bg);
        *(short8*)(&Bs[r0 + 64][c0]) = *(const short8*)(Bg + 64L * K);
        __syncthreads();

        short8 af[4], bf[4];
#pragma unroll
        for (int i = 0; i < 4; i++)
            af[i] = *(const short8*)(&As[wm + i * 16 + mrow][krow]);
#pragma unroll
        for (int j = 0; j < 4; j++)
            bf[j] = *(const short8*)(&Bs[wn + j * 16 + mrow][krow]);

#pragma unroll
        for (int i = 0; i < 4; i++)
#pragma unroll
            for (int j = 0; j < 4; j++)
                acc[i][j] = __builtin_amdgcn_mfma_f32_16x16x32_bf16(
                    af[i], bf[j], acc[i][j], 0, 0, 0);
        __syncthreads();
    }

    const int crow = (lane >> 4) * 4;
    const int ccol = lane & 15;
#pragma unroll
    for (int i = 0; i < 4; i++) {
#pragma unroll
        for (int j = 0; j < 4; j++) {
#pragma unroll
            for (int r = 0; r < 4; r++) {
                long rr = bm + wm + i * 16 + crow + r;
                long cc = bn + wn + j * 16 + ccol;
                float v = acc[i][j][r] * scale;
                if constexpr (__is_same(OutT, float))
                    C[rr * (long)N + cc] = v;
                else
                    C[rr * (long)N + cc] = __float2bfloat16(v);
            }
        }
    }
}

// ---------------------------------------------------------------------------
// Row-wise masked softmax: thr = mean + std(ddof=1)/8; keep s>=thr; softmax.
// One 256-thread block per row, row resident in registers.
// ---------------------------------------------------------------------------
__device__ inline float wred_sum(float x) {
#pragma unroll
    for (int o = 32; o; o >>= 1) x += __shfl_xor(x, o);
    return x;
}
__device__ inline float wred_max(float x) {
#pragma unroll
    for (int o = 32; o; o >>= 1) x = fmaxf(x, __shfl_xor(x, o));
    return x;
}

template <int NK>
__global__ __launch_bounds__(256) void masked_softmax_k(
    const float* __restrict__ S, bf16* __restrict__ P)
{
    constexpr int EPT = NK / 256;
    const long row = blockIdx.x;
    const float* s = S + row * (long)NK;
    bf16* p = P + row * (long)NK;
    const int tid = threadIdx.x;
    const int lane = tid & 63, wave = tid >> 6;

    float v[EPT];
    float sum = 0.f, sq = 0.f, mx = -1e30f;
#pragma unroll
    for (int i = 0; i < EPT; i++) {
        float x = s[tid + i * 256];
        v[i] = x;
        sum += x;
        sq += x * x;
        mx = fmaxf(mx, x);
    }

    __shared__ float red[3][4];
    float a = wred_sum(sum), b2 = wred_sum(sq), c = wred_max(mx);
    if (lane == 0) { red[0][wave] = a; red[1][wave] = b2; red[2][wave] = c; }
    __syncthreads();
    sum = red[0][0] + red[0][1] + red[0][2] + red[0][3];
    sq  = red[1][0] + red[1][1] + red[1][2] + red[1][3];
    mx  = fmaxf(fmaxf(red[2][0], red[2][1]), fmaxf(red[2][2], red[2][3]));

    float mean = sum * (1.0f / NK);
    float var = fmaxf((sq - (float)NK * mean * mean) * (1.0f / (NK - 1)), 0.0f);
    float thr = mean + sqrtf(var) * 0.125f;

    float e[EPT];
    float es = 0.f;
#pragma unroll
    for (int i = 0; i < EPT; i++) {
        float x = (v[i] >= thr) ? __expf(v[i] - mx) : 0.0f;
        e[i] = x;
        es += x;
    }
    __syncthreads();
    float w = wred_sum(es);
    if (lane == 0) red[0][wave] = w;
    __syncthreads();
    es = red[0][0] + red[0][1] + red[0][2] + red[0][3];
    float inv = 1.0f / es;
#pragma unroll
    for (int i = 0; i < EPT; i++)
        p[tid + i * 256] = __float2bfloat16(e[i] * inv);
}

// ---------------------------------------------------------------------------
// fp32 -> bf16 elementwise (n divisible by 4)
// ---------------------------------------------------------------------------
__global__ __launch_bounds__(256) void cvt_f32_bf16(
    const float* __restrict__ in, bf16* __restrict__ out, long n4)
{
    long i = (long)blockIdx.x * 256 + threadIdx.x;
    if (i < n4) {
        float4 f = ((const float4*)in)[i];
        out[i * 4 + 0] = __float2bfloat16(f.x);
        out[i * 4 + 1] = __float2bfloat16(f.y);
        out[i * 4 + 2] = __float2bfloat16(f.z);
        out[i * 4 + 3] = __float2bfloat16(f.w);
    }
}

// ---------------------------------------------------------------------------
// fp32 [R x C] -> bf16 [C x R] tiled transpose (R,C multiples of 32), batched z
// ---------------------------------------------------------------------------
__global__ __launch_bounds__(256) void transpose_f32_bf16(
    const float* __restrict__ in, bf16* __restrict__ out, int R, int C)
{
    __shared__ float tile[32][33];
    const long boff = (long)blockIdx.z * (long)R * C;
    in += boff;
    out += boff;
    const int c0 = blockIdx.x * 32, r0 = blockIdx.y * 32;
    const int tx = threadIdx.x, ty = threadIdx.y;
#pragma unroll
    for (int i = ty; i < 32; i += 8)
        tile[i][tx] = in[(long)(r0 + i) * C + c0 + tx];
    __syncthreads();
#pragma unroll
    for (int i = ty; i < 32; i += 8)
        out[(long)(c0 + i) * R + r0 + tx] = __float2bfloat16(tile[tx][i]);
}

// ---------------------------------------------------------------------------
extern "C" void kernel_launch(void* const* d_in, const int* in_sizes, int n_in,
                              void* d_out, int out_size, void* d_ws, size_t ws_size,
                              hipStream_t stream)
{
    const float* Xp = (const float*)d_in[0];  // [4,4096,512]
    const float* Xc = (const float*)d_in[1];  // [4,1024,512]
    float* out = (float*)d_out;               // [4,4096,1024]

    constexpr int B = 4, NP = 4096, NC = 1024, D = 512;
    constexpr float SCALE = 0.044194173824159216f;  // 1/sqrt(512)

    // workspace layout (bytes) — total ~163.6 MB
    char* ws = (char*)d_ws;
    bf16* Qp  = (bf16*)(ws);                              // B*NP*D bf16 = 16.78 MB
    bf16* Kc  = (bf16*)(ws + 16777216);                   // B*NC*D bf16 =  4.19 MB
    bf16* KcT = (bf16*)(ws + 16777216 + 4194304);         // B*D*NC bf16 =  4.19 MB
    bf16* XpT = (bf16*)(ws + 16777216 + 8388608);         // B*D*NP bf16 = 16.78 MB
    float* S  = (float*)(ws + 41943040);                  // B*NP*NC fp32 = 67.1 MB (reused for S2)
    bf16* Aw  = (bf16*)(ws + 41943040 + 67108864);        // B*NP*NC bf16 = 33.55 MB (reused for A2)
    bf16* H1  = (bf16*)(ws + 41943040 + 100663296);       // B*NP*D  bf16 = 16.78 MB
    bf16* H2  = (bf16*)(ws + 41943040 + 117440512);       // B*NC*D  bf16 =  4.19 MB

    // 1-2: convert inputs to bf16
    {
        long n4 = (long)B * NP * D / 4;
        cvt_f32_bf16<<<dim3((n4 + 255) / 256), dim3(256), 0, stream>>>(Xp, Qp, n4);
        n4 = (long)B * NC * D / 4;
        cvt_f32_bf16<<<dim3((n4 + 255) / 256), dim3(256), 0, stream>>>(Xc, Kc, n4);
    }
    // 3-4: transposed bf16 copies (for the A·B GEMMs recast as A·Bt^T)
    transpose_f32_bf16<<<dim3(D / 32, NC / 32, B), dim3(32, 8), 0, stream>>>(Xc, KcT, NC, D);
    transpose_f32_bf16<<<dim3(D / 32, NP / 32, B), dim3(32, 8), 0, stream>>>(Xp, XpT, NP, D);

    // 5: S1 = Qp * Kc^T * scale      [B, NP, NC] fp32
    gemm_bt<float><<<dim3(NC / 128, NP / 128, B), dim3(256), 0, stream>>>(
        Qp, Kc, S, NP, NC, D, (long)NP * D, (long)NC * D, (long)NP * NC, SCALE);
    // 6: A1 = masked_softmax(S1)     [B, NP, NC] bf16
    masked_softmax_k<NC><<<dim3(B * NP), dim3(256), 0, stream>>>(S, Aw);
    // 7: H1 = A1 * Kc                [B, NP, D] bf16   (A·Bt^T with Bt = Kc^T)
    gemm_bt<bf16><<<dim3(D / 128, NP / 128, B), dim3(256), 0, stream>>>(
        Aw, KcT, H1, NP, D, NC, (long)NP * NC, (long)D * NC, (long)NP * D, 1.0f);
    // 8: S2 = Kc * Qp^T * scale      [B, NC, NP] fp32
    gemm_bt<float><<<dim3(NP / 128, NC / 128, B), dim3(256), 0, stream>>>(
        Kc, Qp, S, NC, NP, D, (long)NC * D, (long)NP * D, (long)NC * NP, SCALE);
    // 9: A2 = masked_softmax(S2)     [B, NC, NP] bf16
    masked_softmax_k<NP><<<dim3(B * NC), dim3(256), 0, stream>>>(S, Aw);
    // 10: H2 = A2 * Xp               [B, NC, D] bf16   (Bt = Xp^T)
    gemm_bt<bf16><<<dim3(D / 128, NC / 128, B), dim3(256), 0, stream>>>(
        Aw, XpT, H2, NC, D, NP, (long)NC * NP, (long)D * NP, (long)NC * D, 1.0f);
    // 11: out = H1 * H2^T            [B, NP, NC] fp32
    gemm_bt<float><<<dim3(NC / 128, NP / 128, B), dim3(256), 0, stream>>>(
        H1, H2, out, NP, NC, D, (long)NP * D, (long)NC * D, (long)NP * NC, 1.0f);
}

// Round 2
// 334.519 us; speedup vs baseline: 1.1932x; 1.1932x over previous
//
#include <hip/hip_runtime.h>
#include <hip/hip_bf16.h>

using bf16 = __hip_bfloat16;
typedef __attribute__((ext_vector_type(8))) short short8;   // 8 bf16 = 4 VGPRs (MFMA A/B frag)
typedef __attribute__((ext_vector_type(4))) float floatx4;  // MFMA C/D frag

// ---------------------------------------------------------------------------
// async global->LDS, 16B per lane. LDS dest = (wave-uniform base) + lane*16B.
// ---------------------------------------------------------------------------
__device__ __forceinline__ void async_copy16(const bf16* g, bf16* l) {
    __builtin_amdgcn_global_load_lds(
        (const __attribute__((address_space(1))) unsigned int*)g,
        (__attribute__((address_space(3))) unsigned int*)l,
        16, 0, 0);
}

// ---------------------------------------------------------------------------
// C[M x N] = scale * A[M x K] (row-major bf16) * Bt[N x K]^T (row-major bf16)
// 128x128 block tile, BK=32, 256 threads = 4 waves in 2x2, each wave 64x64
// via 4x4 grid of v_mfma_f32_16x16x32_bf16. global_load_lds staging (m97):
// unpadded [128][32] LDS; wave w stages rows [32w, 32w+32), lane l -> row
// l>>2, col (l&3)*8 so LDS dest == base + lane*16B.
// Split-K: gridDim.z = splits*nbat, z = s*nbat + b; partial slot s at
// C + z*strideC (layout [s][b][M][N]).
// Verified layouts (cdna_hip_programming.md §3):
//   A frag: lane holds A[m = lane&15][k = (lane>>4)*8 + j], j=0..7
//   C/D   : col = lane&15, row = (lane>>4)*4 + reg
// ---------------------------------------------------------------------------
template <typename OutT>
__global__ __launch_bounds__(256) void gemm_bt(
    const bf16* __restrict__ A, const bf16* __restrict__ B, OutT* __restrict__ C,
    int M, int N, int K, long strideA, long strideB, long strideC,
    float scale, int nbat, int splits)
{
    const int z = blockIdx.z;
    const int b = z % nbat;
    const int s = z / nbat;
    const int klen = K / splits;
    const int k0 = s * klen;

    A += (long)b * strideA;
    B += (long)b * strideB;
    C += (long)z * strideC;

    const int bm = blockIdx.y * 128;
    const int bn = blockIdx.x * 128;
    const int tid = threadIdx.x;
    const int lane = tid & 63;
    const int wave = tid >> 6;
    const int wm = (wave >> 1) * 64;
    const int wn = (wave & 1) * 64;

    __shared__ bf16 As[128][32];
    __shared__ bf16 Bs[128][32];

    floatx4 acc[4][4];
#pragma unroll
    for (int i = 0; i < 4; i++)
#pragma unroll
        for (int j = 0; j < 4; j++) acc[i][j] = (floatx4)(0.0f);

    // staging addresses: wave stages its 32 rows of A and B per K-tile
    const int srow = lane >> 2;        // 0..15
    const int scol = (lane & 3) * 8;   // bf16 elems: 0,8,16,24

    const int mrow = lane & 15;
    const int krow = (lane >> 4) * 8;

    for (int kb = k0; kb < k0 + klen; kb += 32) {
        const bf16* Ag = A + (long)(bm + wave * 32 + srow) * K + kb + scol;
        const bf16* Bg = B + (long)(bn + wave * 32 + srow) * K + kb + scol;
        async_copy16(Ag,            &As[wave * 32][0]);
        async_copy16(Ag + 16L * K,  &As[wave * 32 + 16][0]);
        async_copy16(Bg,            &Bs[wave * 32][0]);
        async_copy16(Bg + 16L * K,  &Bs[wave * 32 + 16][0]);
        __syncthreads();

        short8 af[4], bf[4];
#pragma unroll
        for (int i = 0; i < 4; i++)
            af[i] = *(const short8*)(&As[wm + i * 16 + mrow][krow]);
#pragma unroll
        for (int j = 0; j < 4; j++)
            bf[j] = *(const short8*)(&Bs[wn + j * 16 + mrow][krow]);

#pragma unroll
        for (int i = 0; i < 4; i++)
#pragma unroll
            for (int j = 0; j < 4; j++)
                acc[i][j] = __builtin_amdgcn_mfma_f32_16x16x32_bf16(
                    af[i], bf[j], acc[i][j], 0, 0, 0);
        __syncthreads();
    }

    const int crow = (lane >> 4) * 4;
    const int ccol = lane & 15;
#pragma unroll
    for (int i = 0; i < 4; i++) {
#pragma unroll
        for (int j = 0; j < 4; j++) {
#pragma unroll
            for (int r = 0; r < 4; r++) {
                long rr = bm + wm + i * 16 + crow + r;
                long cc = bn + wn + j * 16 + ccol;
                float v = acc[i][j][r] * scale;
                if constexpr (__is_same(OutT, float))
                    C[rr * (long)N + cc] = v;
                else
                    C[rr * (long)N + cc] = __float2bfloat16(v);
            }
        }
    }
}

// ---------------------------------------------------------------------------
// Sum S split-K fp32 partials (slot stride = stride elems) -> bf16
// ---------------------------------------------------------------------------
template <int S>
__global__ __launch_bounds__(256) void reduce_splits_bf16(
    const float* __restrict__ P, bf16* __restrict__ out, long n4, long stride)
{
    long i = (long)blockIdx.x * 256 + threadIdx.x;
    if (i < n4) {
        float4 a = ((const float4*)P)[i];
#pragma unroll
        for (int s = 1; s < S; s++) {
            float4 b = ((const float4*)(P + (long)s * stride))[i];
            a.x += b.x; a.y += b.y; a.z += b.z; a.w += b.w;
        }
        out[i * 4 + 0] = __float2bfloat16(a.x);
        out[i * 4 + 1] = __float2bfloat16(a.y);
        out[i * 4 + 2] = __float2bfloat16(a.z);
        out[i * 4 + 3] = __float2bfloat16(a.w);
    }
}

// ---------------------------------------------------------------------------
// Row-wise masked softmax: thr = mean + std(ddof=1)/8; keep s>=thr; softmax.
// One 256-thread block per row, row resident in registers.
// ---------------------------------------------------------------------------
__device__ inline float wred_sum(float x) {
#pragma unroll
    for (int o = 32; o; o >>= 1) x += __shfl_xor(x, o);
    return x;
}
__device__ inline float wred_max(float x) {
#pragma unroll
    for (int o = 32; o; o >>= 1) x = fmaxf(x, __shfl_xor(x, o));
    return x;
}

template <int NK>
__global__ __launch_bounds__(256) void masked_softmax_k(
    const float* __restrict__ S, bf16* __restrict__ P)
{
    constexpr int EPT = NK / 256;
    const long row = blockIdx.x;
    const float* s = S + row * (long)NK;
    bf16* p = P + row * (long)NK;
    const int tid = threadIdx.x;
    const int lane = tid & 63, wave = tid >> 6;

    float v[EPT];
    float sum = 0.f, sq = 0.f, mx = -1e30f;
#pragma unroll
    for (int i = 0; i < EPT; i++) {
        float x = s[tid + i * 256];
        v[i] = x;
        sum += x;
        sq += x * x;
        mx = fmaxf(mx, x);
    }

    __shared__ float red[3][4];
    float a = wred_sum(sum), b2 = wred_sum(sq), c = wred_max(mx);
    if (lane == 0) { red[0][wave] = a; red[1][wave] = b2; red[2][wave] = c; }
    __syncthreads();
    sum = red[0][0] + red[0][1] + red[0][2] + red[0][3];
    sq  = red[1][0] + red[1][1] + red[1][2] + red[1][3];
    mx  = fmaxf(fmaxf(red[2][0], red[2][1]), fmaxf(red[2][2], red[2][3]));

    float mean = sum * (1.0f / NK);
    float var = fmaxf((sq - (float)NK * mean * mean) * (1.0f / (NK - 1)), 0.0f);
    float thr = mean + sqrtf(var) * 0.125f;

    float e[EPT];
    float es = 0.f;
#pragma unroll
    for (int i = 0; i < EPT; i++) {
        float x = (v[i] >= thr) ? __expf(v[i] - mx) : 0.0f;
        e[i] = x;
        es += x;
    }
    __syncthreads();
    float w = wred_sum(es);
    if (lane == 0) red[0][wave] = w;
    __syncthreads();
    es = red[0][0] + red[0][1] + red[0][2] + red[0][3];
    float inv = 1.0f / es;
#pragma unroll
    for (int i = 0; i < EPT; i++)
        p[tid + i * 256] = __float2bfloat16(e[i] * inv);
}

// ---------------------------------------------------------------------------
// fp32 -> bf16 elementwise (n divisible by 4)
// ---------------------------------------------------------------------------
__global__ __launch_bounds__(256) void cvt_f32_bf16(
    const float* __restrict__ in, bf16* __restrict__ out, long n4)
{
    long i = (long)blockIdx.x * 256 + threadIdx.x;
    if (i < n4) {
        float4 f = ((const float4*)in)[i];
        out[i * 4 + 0] = __float2bfloat16(f.x);
        out[i * 4 + 1] = __float2bfloat16(f.y);
        out[i * 4 + 2] = __float2bfloat16(f.z);
        out[i * 4 + 3] = __float2bfloat16(f.w);
    }
}

// ---------------------------------------------------------------------------
// fp32 [R x C] -> bf16 [C x R] tiled transpose (R,C multiples of 32), batched z
// ---------------------------------------------------------------------------
__global__ __launch_bounds__(256) void transpose_f32_bf16(
    const float* __restrict__ in, bf16* __restrict__ out, int R, int C)
{
    __shared__ float tile[32][33];
    const long boff = (long)blockIdx.z * (long)R * C;
    in += boff;
    out += boff;
    const int c0 = blockIdx.x * 32, r0 = blockIdx.y * 32;
    const int tx = threadIdx.x, ty = threadIdx.y;
#pragma unroll
    for (int i = ty; i < 32; i += 8)
        tile[i][tx] = in[(long)(r0 + i) * C + c0 + tx];
    __syncthreads();
#pragma unroll
    for (int i = ty; i < 32; i += 8)
        out[(long)(c0 + i) * R + r0 + tx] = __float2bfloat16(tile[tx][i]);
}

// ---------------------------------------------------------------------------
extern "C" void kernel_launch(void* const* d_in, const int* in_sizes, int n_in,
                              void* d_out, int out_size, void* d_ws, size_t ws_size,
                              hipStream_t stream)
{
    const float* Xp = (const float*)d_in[0];  // [4,4096,512]
    const float* Xc = (const float*)d_in[1];  // [4,1024,512]
    float* out = (float*)d_out;               // [4,4096,1024]

    constexpr int B = 4, NP = 4096, NC = 1024, D = 512;
    constexpr float SCALE = 0.044194173824159216f;  // 1/sqrt(512)

    // workspace layout (bytes) — total ~163.6 MB
    char* ws = (char*)d_ws;
    bf16* Qp  = (bf16*)(ws);                              // B*NP*D bf16 = 16.78 MB
    bf16* Kc  = (bf16*)(ws + 16777216);                   // B*NC*D bf16 =  4.19 MB
    bf16* KcT = (bf16*)(ws + 16777216 + 4194304);         // B*D*NC bf16 =  4.19 MB
    bf16* XpT = (bf16*)(ws + 16777216 + 8388608);         // B*D*NP bf16 = 16.78 MB
    float* S  = (float*)(ws + 41943040);                  // B*NP*NC fp32 = 67.1 MB (reused: S2, then H2 partials)
    bf16* Aw  = (bf16*)(ws + 41943040 + 67108864);        // B*NP*NC bf16 = 33.55 MB (reused for A2)
    bf16* H1  = (bf16*)(ws + 41943040 + 100663296);       // B*NP*D  bf16 = 16.78 MB
    bf16* H2  = (bf16*)(ws + 41943040 + 117440512);       // B*NC*D  bf16 =  4.19 MB
    float* Hp = S;  // step-10 split-K partials [4][B][NC][D] fp32 = 33.5 MB (S dead after step 9)

    // 1-2: convert inputs to bf16
    {
        long n4 = (long)B * NP * D / 4;
        cvt_f32_bf16<<<dim3((n4 + 255) / 256), dim3(256), 0, stream>>>(Xp, Qp, n4);
        n4 = (long)B * NC * D / 4;
        cvt_f32_bf16<<<dim3((n4 + 255) / 256), dim3(256), 0, stream>>>(Xc, Kc, n4);
    }
    // 3-4: transposed bf16 copies (for the A·B GEMMs recast as A·Bt^T)
    transpose_f32_bf16<<<dim3(D / 32, NC / 32, B), dim3(32, 8), 0, stream>>>(Xc, KcT, NC, D);
    transpose_f32_bf16<<<dim3(D / 32, NP / 32, B), dim3(32, 8), 0, stream>>>(Xp, XpT, NP, D);

    // 5: S1 = Qp * Kc^T * scale      [B, NP, NC] fp32
    gemm_bt<float><<<dim3(NC / 128, NP / 128, B), dim3(256), 0, stream>>>(
        Qp, Kc, S, NP, NC, D, (long)NP * D, (long)NC * D, (long)NP * NC, SCALE, B, 1);
    // 6: A1 = masked_softmax(S1)     [B, NP, NC] bf16
    masked_softmax_k<NC><<<dim3(B * NP), dim3(256), 0, stream>>>(S, Aw);
    // 7: H1 = A1 * Kc                [B, NP, D] bf16   (A·Bt^T with Bt = Kc^T)
    gemm_bt<bf16><<<dim3(D / 128, NP / 128, B), dim3(256), 0, stream>>>(
        Aw, KcT, H1, NP, D, NC, (long)NP * NC, (long)D * NC, (long)NP * D, 1.0f, B, 1);
    // 8: S2 = Kc * Qp^T * scale      [B, NC, NP] fp32
    gemm_bt<float><<<dim3(NP / 128, NC / 128, B), dim3(256), 0, stream>>>(
        Kc, Qp, S, NC, NP, D, (long)NC * D, (long)NP * D, (long)NC * NP, SCALE, B, 1);
    // 9: A2 = masked_softmax(S2)     [B, NC, NP] bf16
    masked_softmax_k<NP><<<dim3(B * NC), dim3(256), 0, stream>>>(S, Aw);
    // 10: H2 = A2 * Xp               [B, NC, D] bf16   (Bt = Xp^T), 4-way split-K
    gemm_bt<float><<<dim3(D / 128, NC / 128, 4 * B), dim3(256), 0, stream>>>(
        Aw, XpT, Hp, NC, D, NP, (long)NC * NP, (long)D * NP, (long)NC * D, 1.0f, B, 4);
    {
        long n = (long)B * NC * D;
        reduce_splits_bf16<4><<<dim3((n / 4 + 255) / 256), dim3(256), 0, stream>>>(
            Hp, H2, n / 4, n);
    }
    // 11: out = H1 * H2^T            [B, NP, NC] fp32
    gemm_bt<float><<<dim3(NC / 128, NP / 128, B), dim3(256), 0, stream>>>(
        H1, H2, out, NP, NC, D, (long)NP * D, (long)NC * D, (long)NP * NC, 1.0f, B, 1);
}